// Round 9
// baseline (94.611 us; speedup 1.0000x reference)
//
#include <hip/hip_runtime.h>

#define IMG_W 1024
#define IMG_H 1024
#define ROW_F 72                    // f32 per LDS row: cols bx*64-4 .. bx*64+67
#define LDS_F 5120                  // 5 DMA rounds x 1024 dwords (rows 0..71, junk >67 unread)

// Packed 2 x f16: one VGPR = one window position for two adjacent output px.
typedef _Float16 h2 __attribute__((ext_vector_type(2)));
typedef __attribute__((address_space(3))) unsigned lds_u32_t;
typedef const __attribute__((address_space(1))) unsigned glb_u32_t;

__device__ __forceinline__ h2 mn(h2 a, h2 b) { return __builtin_elementwise_min(a, b); }
__device__ __forceinline__ h2 mx(h2 a, h2 b) { return __builtin_elementwise_max(a, b); }
__device__ __forceinline__ void ce(h2 &a, h2 &b) { h2 t = mn(a, b); b = mx(a, b); a = t; }
__device__ __forceinline__ h2 med3p(h2 a, h2 b, h2 c) {
    return mx(mn(a, b), mn(mx(a, b), c));
}
// cvt_pkrtz returns __fp16 ext_vector(2); bit_cast to our h2 (same 4B layout).
__device__ __forceinline__ h2 pkrtz(float a, float b) {
    return __builtin_bit_cast(h2, __builtin_amdgcn_cvt_pkrtz(a, b));
}
// 9-CE optimal sort5 (validated rounds 1-7)
__device__ __forceinline__ void sort5(h2 &a0, h2 &a1, h2 &a2, h2 &a3, h2 &a4) {
    ce(a0, a1); ce(a3, a4); ce(a2, a4); ce(a2, a3);
    ce(a0, a3); ce(a0, a2); ce(a1, a4); ce(a1, a3); ce(a1, a2);
}
// 5-CE sort4
__device__ __forceinline__ void sort4(h2 &a, h2 &b, h2 &c, h2 &d) {
    ce(a, b); ce(c, d); ce(a, c); ce(b, d); ce(b, c);
}

struct Row { h2 a, b, c, d, e; };         // sorted 5-wide window (packed 2 px)
struct Raw { float2 f01, f23, f45; };     // 6 f32 of one tile row's window span

__device__ __forceinline__ Raw load_raw(const float* __restrict__ ldsf, int row, int tx) {
    const float* p = ldsf + row * ROW_F + 2 * tx + 2;   // rel col 2tx+2 <-> gcol 2tx-2
    Raw r;
    r.f01 = *reinterpret_cast<const float2*>(p);
    r.f23 = *reinterpret_cast<const float2*>(p + 2);
    r.f45 = *reinterpret_cast<const float2*>(p + 4);
    return r;
}
// cvt f32->packed f16 (RTZ, monotone -> median = f16(true median)), then sort.
__device__ __forceinline__ Row sort_row(Raw r) {
    h2 p0 = pkrtz(r.f01.x, r.f01.y);
    h2 p1 = pkrtz(r.f01.y, r.f23.x);
    h2 p2 = pkrtz(r.f23.x, r.f23.y);
    h2 p3 = pkrtz(r.f23.y, r.f45.x);
    h2 p4 = pkrtz(r.f45.x, r.f45.y);
    sort5(p0, p1, p2, p3, p4);
    return {p0, p1, p2, p3, p4};
}

// Forgetful selection: median (rank 6) of the 13 candidates (validated rounds 1-7).
__device__ __forceinline__ h2 tail13(h2 A, h2 B, h2 c1a, h2 c1b, h2 c1c,
                                     h2 c2a, h2 c2b, h2 c2c,
                                     h2 c3a, h2 c3b, h2 c3c, h2 D, h2 E) {
    ce(A, D); ce(c1a, c3a); ce(A, c1a);        // A = min8 (drop)
    ce(B, E); ce(c1b, c3b); ce(E, c3b);        // c3b = max8 (drop)
    h2 e0 = B, e1 = D, e2 = E, e3 = c1a, e4 = c1b, e5 = c3a, e6 = c1c;
    ce(e0, e1); ce(e2, e3); ce(e4, e5);
    ce(e0, e2); ce(e4, e6); ce(e0, e4);        // e0 = min7 (drop)
    ce(e1, e3); ce(e5, e6); ce(e3, e6);        // e6 = max7 (drop)
    h2 f0 = e1, f1 = e2, f2 = e3, f3 = e4, f4 = e5, f5 = c2a;
    ce(f0, f1); ce(f2, f3); ce(f4, f5);
    ce(f0, f2); ce(f0, f4);                    // f0 = min6 (drop)
    ce(f1, f3); ce(f3, f5);                    // f5 = max6 (drop)
    h2 g0 = f1, g1 = f2, g2 = f3, g3 = f4, g4 = c2b;
    ce(g0, g1); ce(g2, g3);
    ce(g0, g2); ce(g0, g4);                    // g0 = min5 (drop)
    ce(g1, g3); ce(g3, g4);                    // g4 = max5 (drop)
    h2 h0 = g1, h1 = g2, h2_ = g3, h3 = c2c;
    ce(h0, h1); ce(h2_, h3); ce(h0, h2_); ce(h1, h3);
    return med3p(h1, h2_, c3c);
}

// Two vertically adjacent windows sharing rows rb..re (validated rounds 4-7).
__device__ __forceinline__ void pair_medians(const Row &rb, const Row &rc, const Row &rd,
                                             const Row &re, const Row &ra, const Row &rf,
                                             h2 &out_lo, h2 &out_hi) {
    h2 s0, s1, s2, s3;
    s0 = rb.a; s1 = rc.a; s2 = rd.a; s3 = re.a; sort4(s0, s1, s2, s3);
    h2 Bl = mx(s3, ra.a), Al = mx(s2, mn(s3, ra.a));
    h2 Bh = mx(s3, rf.a), Ah = mx(s2, mn(s3, rf.a));
    s0 = rb.b; s1 = rc.b; s2 = rd.b; s3 = re.b; sort4(s0, s1, s2, s3);
    h2 c1al = s2, c1bl = s3, c1cl = mx(s1, ra.b);
    h2 c1ah = s2, c1bh = s3, c1ch = mx(s1, rf.b);
    s0 = rb.c; s1 = rc.c; s2 = rd.c; s3 = re.c; sort4(s0, s1, s2, s3);
    h2 c2al = s1, c2bl = s2, c2cl = med3p(s0, ra.c, s3);
    h2 c2ah = s1, c2bh = s2, c2ch = med3p(s0, rf.c, s3);
    s0 = rb.d; s1 = rc.d; s2 = rd.d; s3 = re.d; sort4(s0, s1, s2, s3);
    h2 c3al = s0, c3bl = s1, c3cl = mn(s2, ra.d);
    h2 c3ah = s0, c3bh = s1, c3ch = mn(s2, rf.d);
    s0 = rb.e; s1 = rc.e; s2 = rd.e; s3 = re.e; sort4(s0, s1, s2, s3);
    h2 Dl = mn(s0, ra.e), El = mn(s1, mx(s0, ra.e));
    h2 Dh = mn(s0, rf.e), Eh = mn(s1, mx(s0, rf.e));

    out_lo = tail13(Al, Bl, c1al, c1bl, c1cl, c2al, c2bl, c2cl, c3al, c3bl, c3cl, Dl, El);
    out_hi = tail13(Ah, Bh, c1ah, c1bh, c1ch, c2ah, c2bh, c2ch, c3ah, c3bh, c3ch, Dh, Eh);
}

// Block 32x8; tile 64x64 outputs; lane = 2 cols x 8 rows x (pairs) = 16 px.
__global__ __launch_bounds__(256, 6) void median5x5_kernel(const float* __restrict__ x,
                                                           float* __restrict__ out) {
    __shared__ float ldsf[LDS_F];            // 20 KB, f32 tile rows of ROW_F

    const int tx = threadIdx.x;              // 0..31
    const int ty = threadIdx.y;              // 0..7
    const int tid = ty * 32 + tx;
    const int bx = blockIdx.x, by = blockIdx.y;
    const int plane = blockIdx.z;
    const float* src = x + (size_t)plane * IMG_H * IMG_W;

    const int gx0a = bx * 64 - 4;            // LDS rel col 0 <-> global col gx0a (16B aligned)
    const int gy0 = by * 64 - 2;             // LDS row 0 <-> global row gy0

    const bool border = (bx == 0) | (bx == 15) | (by == 0) | (by == 15);
    if (!border) {
        // ---- interior: direct global->LDS DMA, no VGPR round-trip ----
        // issue k, wave w, lane L: lds byte off = (k*256+tid)*16 = wavebase + L*16
        // (exactly the HW wave-uniform-base + lane*16 pattern). Rows 68..71 are
        // junk (in-bounds reads, never consumed).
        const float* srcb = src + (size_t)gy0 * IMG_W + gx0a;
        #pragma unroll
        for (int k = 0; k < 5; ++k) {
            int q = k * 256 + tid;           // 4-float chunk index
            int row = q / 18;                // 18 chunks per 72-float row
            int c4 = q - row * 18;
            const float* g = srcb + row * IMG_W + c4 * 4;
            __builtin_amdgcn_global_load_lds((glb_u32_t*)g, (lds_u32_t*)&ldsf[q * 4],
                                             16, 0, 0);
        }
        asm volatile("s_waitcnt vmcnt(0)" ::: "memory");
    } else {
        // ---- border: guarded float2 loads, zero-pad, ds_write_b64 ----
        #pragma unroll
        for (int k = 0; k < 10; ++k) {
            int idx = tid + k * 256;         // float2 cell; 68 rows x 36 cells
            if (idx < 68 * 36) {
                int r = idx / 36;
                int dc = idx - r * 36;
                int gy = gy0 + r;
                int gxa = gx0a + 2 * dc;
                int cgy = min(max(gy, 0), IMG_H - 1);
                int cgx = min(max(gxa, 0), IMG_W - 2);
                float2 v = *reinterpret_cast<const float2*>(src + (size_t)cgy * IMG_W + cgx);
                bool rowok = (unsigned)gy < (unsigned)IMG_H;
                float a = (rowok && (unsigned)gxa < (unsigned)IMG_W) ? v.x : 0.0f;
                float b = (rowok && (unsigned)(gxa + 1) < (unsigned)IMG_W) ? v.y : 0.0f;
                float2 w2; w2.x = a; w2.y = b;
                *reinterpret_cast<float2*>(&ldsf[r * ROW_F + 2 * dc]) = w2;
            }
        }
    }
    __syncthreads();

    const int base = ty * 8;
    Raw r0 = load_raw(ldsf, base + 0, tx), r1 = load_raw(ldsf, base + 1, tx),
        r2 = load_raw(ldsf, base + 2, tx), r3 = load_raw(ldsf, base + 3, tx),
        r4 = load_raw(ldsf, base + 4, tx), r5 = load_raw(ldsf, base + 5, tx);
    Row S0 = sort_row(r0), S1 = sort_row(r1), S2 = sort_row(r2),
        S3 = sort_row(r3), S4 = sort_row(r4), S5 = sort_row(r5);

    float* dst = out + (size_t)plane * IMG_H * IMG_W
               + (size_t)(by * 64 + base) * IMG_W + bx * 64 + 2 * tx;
    h2 mlo, mhi;

#define EMIT(vv, m) do {                                                       \
        float2 o; o.x = (float)(m).x; o.y = (float)(m).y;                      \
        *reinterpret_cast<float2*>(dst + (size_t)(vv) * IMG_W) = o;            \
    } while (0)

    Raw n0 = load_raw(ldsf, base + 6, tx), n1 = load_raw(ldsf, base + 7, tx);
    pair_medians(S1, S2, S3, S4, S0, S5, mlo, mhi);   // windows 0-4 / 1-5
    EMIT(0, mlo); EMIT(1, mhi);
    S0 = sort_row(n0); S1 = sort_row(n1);

    n0 = load_raw(ldsf, base + 8, tx); n1 = load_raw(ldsf, base + 9, tx);
    pair_medians(S3, S4, S5, S0, S2, S1, mlo, mhi);   // windows 2-6 / 3-7
    EMIT(2, mlo); EMIT(3, mhi);
    S2 = sort_row(n0); S3 = sort_row(n1);

    n0 = load_raw(ldsf, base + 10, tx); n1 = load_raw(ldsf, base + 11, tx);
    pair_medians(S5, S0, S1, S2, S4, S3, mlo, mhi);   // windows 4-8 / 5-9
    EMIT(4, mlo); EMIT(5, mhi);
    S4 = sort_row(n0); S5 = sort_row(n1);

    pair_medians(S1, S2, S3, S4, S0, S5, mlo, mhi);   // windows 6-10 / 7-11
    EMIT(6, mlo); EMIT(7, mhi);
#undef EMIT
}

extern "C" void kernel_launch(void* const* d_in, const int* in_sizes, int n_in,
                              void* d_out, int out_size, void* d_ws, size_t ws_size,
                              hipStream_t stream) {
    const float* x = (const float*)d_in[0];
    float* out = (float*)d_out;
    const int planes = in_sizes[0] / (IMG_H * IMG_W);   // B*C = 8
    dim3 grid(IMG_W / 64, IMG_H / 64, planes);
    dim3 block(32, 8);
    median5x5_kernel<<<grid, block, 0, stream>>>(x, out);
}